// Round 3
// baseline (293.111 us; speedup 1.0000x reference)
//
#include <hip/hip_runtime.h>

// Problem: B=8, S=2048, D=512, DK=64.
// out = attended [8,2048,64] fp32  ||  weights [8,2048,2048] fp32

typedef __bf16 bf16x8 __attribute__((ext_vector_type(8)));
typedef float f32x4 __attribute__((ext_vector_type(4)));

__device__ __forceinline__ short f2bf(float f) {
    unsigned u = __builtin_bit_cast(unsigned, f);
    u = (u + 0x7fffu + ((u >> 16) & 1u)) >> 16;
    return (short)u;
}
__device__ __forceinline__ float bf2f(short h) {
    unsigned u = ((unsigned)(unsigned short)h) << 16;
    return __builtin_bit_cast(float, u);
}
__device__ __forceinline__ bf16x8 ldfrag(const short* p) {
    return *reinterpret_cast<const bf16x8*>(p);
}
__device__ __forceinline__ f32x4 mfma16(bf16x8 a, bf16x8 b, f32x4 c) {
    return __builtin_amdgcn_mfma_f32_16x16x32_bf16(a, b, c, 0, 0, 0);
}

// ---------------------------------------------------------------------------
// Kernel 0: W [512,64] fp32 -> WT [m][64][512] bf16, hi/lo split for q,k.
// ---------------------------------------------------------------------------
__global__ void wtrans_kernel(const float* __restrict__ Wq,
                              const float* __restrict__ Wk,
                              const float* __restrict__ Wv,
                              short* __restrict__ wt_hi,
                              short* __restrict__ wt_lo) {
    int idx = blockIdx.x * 256 + threadIdx.x;  // 3*64*512 = 98304 total
    int k = idx & 511;
    int n = (idx >> 9) & 63;
    int m = idx >> 15;  // 0=q,1=k,2=v
    const float* W = (m == 0) ? Wq : (m == 1) ? Wk : Wv;
    float w = W[k * 64 + n];
    short hi = f2bf(w);
    wt_hi[idx] = hi;
    if (m < 2) wt_lo[idx] = f2bf(w - bf2f(hi));
}

// ---------------------------------------------------------------------------
// Kernel 1: QKV projection (verified round-0 version, unchanged).
// ---------------------------------------------------------------------------
__global__ __launch_bounds__(256) void qkv_kernel(
    const float* __restrict__ x,
    const short* __restrict__ wt_hi, const short* __restrict__ wt_lo,
    short* __restrict__ Qg, short* __restrict__ Kg, short* __restrict__ VTg) {
  __shared__ __align__(16) short Ah[32 * 40], Al[32 * 40];     // also vt reuse
  __shared__ __align__(16) short Bqh[64 * 40], Bql[64 * 40];
  __shared__ __align__(16) short Bkh[64 * 40], Bkl[64 * 40];
  __shared__ __align__(16) short Bvh[64 * 40];
  const int t = threadIdx.x;
  const int wave = t >> 6, lane = t & 63, quad = lane >> 4, l15 = lane & 15;
  const int rg = wave & 1, ntp = wave >> 1;
  const int rbase = blockIdx.x * 32;

  f32x4 accq[2] = {}, acck[2] = {}, accv[2] = {};

  for (int k0 = 0; k0 < 512; k0 += 32) {
    {
      int row = t >> 3, off = (t & 7) << 2;
      float4 v = *(const float4*)(x + (size_t)(rbase + row) * 512 + k0 + off);
      short4 h, lo;
      h.x = f2bf(v.x); lo.x = f2bf(v.x - bf2f(h.x));
      h.y = f2bf(v.y); lo.y = f2bf(v.y - bf2f(h.y));
      h.z = f2bf(v.z); lo.z = f2bf(v.z - bf2f(h.z));
      h.w = f2bf(v.w); lo.w = f2bf(v.w - bf2f(h.w));
      *(short4*)(Ah + row * 40 + off) = h;
      *(short4*)(Al + row * 40 + off) = lo;
    }
    {
      int row = t >> 2, off = (t & 3) << 3;
      int src = row * 512 + k0 + off;
      int dst = row * 40 + off;
      *(int4*)(Bqh + dst) = *(const int4*)(wt_hi + 0 * 32768 + src);
      *(int4*)(Bkh + dst) = *(const int4*)(wt_hi + 1 * 32768 + src);
      *(int4*)(Bvh + dst) = *(const int4*)(wt_hi + 2 * 32768 + src);
      *(int4*)(Bql + dst) = *(const int4*)(wt_lo + 0 * 32768 + src);
      *(int4*)(Bkl + dst) = *(const int4*)(wt_lo + 1 * 32768 + src);
    }
    __syncthreads();
    bf16x8 ah = ldfrag(Ah + (rg * 16 + l15) * 40 + quad * 8);
    bf16x8 al = ldfrag(Al + (rg * 16 + l15) * 40 + quad * 8);
    #pragma unroll
    for (int j = 0; j < 2; j++) {
      const int nt = ntp * 2 + j;
      const int boff = (nt * 16 + l15) * 40 + quad * 8;
      bf16x8 bh = ldfrag(Bqh + boff);
      accq[j] = mfma16(ah, bh, accq[j]);
      accq[j] = mfma16(al, bh, accq[j]);
      accq[j] = mfma16(ah, ldfrag(Bql + boff), accq[j]);
      bh = ldfrag(Bkh + boff);
      acck[j] = mfma16(ah, bh, acck[j]);
      acck[j] = mfma16(al, bh, acck[j]);
      acck[j] = mfma16(ah, ldfrag(Bkl + boff), acck[j]);
      accv[j] = mfma16(ah, ldfrag(Bvh + boff), accv[j]);
    }
    __syncthreads();
  }
  #pragma unroll
  for (int j = 0; j < 2; j++) {
    const int nt = ntp * 2 + j;
    #pragma unroll
    for (int r = 0; r < 4; r++) {
      int row = rbase + rg * 16 + quad * 4 + r;
      int col = nt * 16 + l15;
      Qg[(size_t)row * 64 + col] = f2bf(accq[j][r]);
      Kg[(size_t)row * 64 + col] = f2bf(acck[j][r]);
    }
  }
  short* vt = Ah;
  #pragma unroll
  for (int j = 0; j < 2; j++) {
    const int col = (ntp * 2 + j) * 16 + l15;
    short4 p;
    p.x = f2bf(accv[j][0]); p.y = f2bf(accv[j][1]);
    p.z = f2bf(accv[j][2]); p.w = f2bf(accv[j][3]);
    *(short4*)(vt + col * 40 + rg * 16 + quad * 4) = p;
  }
  __syncthreads();
  {
    const int bidx = rbase >> 11;
    int c = t >> 2, ch = (t & 3) << 3;
    *(int4*)(VTg + (size_t)bidx * 131072 + (size_t)c * 2048 + (rbase & 2047) + ch) =
        *(const int4*)(vt + c * 40 + ch);
  }
}

// ---------------------------------------------------------------------------
// Kernel 2: fused attention = R0 LDS staging (latency hiding) + R1 swapped
// QK layout (verified numerics) + T14 async-stage split (reg prefetch).
// grid(8, 64), 256 thr. Wave w: q-rows rg=w&1, s-half half=w>>1.
// Swapped QK^T: mfma(K,Q) -> C[s=quad*4+r][q=l15]:
//   pass-1 l is lane-local (2 shuffles total); weights stored f32x4 straight
//   from registers (16 rows x 64 contiguous B per instr); small per-wave
//   bf16 P buffer for PV (wave-private, lgkmcnt-fenced).
// Constant-shift softmax (C=16, provably safe).
// ---------------------------------------------------------------------------
__device__ __forceinline__ void load_k_regs(int4 (&kr)[4], const short* Kb,
                                            int s0, int t) {
  #pragma unroll
  for (int i = 0; i < 4; i++) {
    int c = t + i * 256, row = c >> 3, off = (c & 7) << 3;
    kr[i] = *(const int4*)(Kb + (size_t)(s0 + row) * 64 + off);
  }
}
__device__ __forceinline__ void store_k_lds(const int4 (&kr)[4], short* Ks,
                                            int t) {
  #pragma unroll
  for (int i = 0; i < 4; i++) {
    int c = t + i * 256, row = c >> 3, off = (c & 7) << 3;
    *(int4*)(Ks + row * 72 + off) = kr[i];
  }
}
__device__ __forceinline__ void load_v_regs(int4 (&vr)[4], const short* Vb,
                                            int s0, int t) {
  #pragma unroll
  for (int i = 0; i < 4; i++) {
    int c = t + i * 256, row = c >> 4, off = (c & 15) << 3;
    vr[i] = *(const int4*)(Vb + (size_t)row * 2048 + s0 + off);
  }
}
__device__ __forceinline__ void store_v_lds(const int4 (&vr)[4], short* Vs,
                                            int t) {
  #pragma unroll
  for (int i = 0; i < 4; i++) {
    int c = t + i * 256, row = c >> 4, off = (c & 15) << 3;
    *(int4*)(Vs + row * 136 + off) = vr[i];
  }
}

__global__ __launch_bounds__(256) void attn_kernel(
    const short* __restrict__ Qg, const short* __restrict__ Kg,
    const short* __restrict__ VTg,
    float* __restrict__ att_out, float* __restrict__ w_out) {
  __shared__ __align__(16) short Ks[128 * 72];   // 18432 B
  __shared__ __align__(16) short Vs[64 * 136];   // 17408 B
  __shared__ __align__(16) short Plds[4 * 16 * 72];  // per-wave P, 9216 B
  __shared__ float Lb[4][16];
  __shared__ float Ob[32 * 68];                  // 8704 B
  const int t = threadIdx.x;
  const int wave = t >> 6, lane = t & 63, quad = lane >> 4, l15 = lane & 15;
  const int rg = wave & 1, half = wave >> 1;
  const int b = blockIdx.x;
  const int qbase = blockIdx.y * 32;
  const float sc2 = 0.125f * 1.44269504088896340736f;  // (1/sqrt(64))*log2(e)
  const float C0 = 16.0f;

  const short* Kb = Kg + (size_t)b * 131072;
  const short* Vb = VTg + (size_t)b * 131072;
  const short* qp =
      Qg + (size_t)(b * 2048 + qbase + rg * 16 + l15) * 64 + quad * 8;
  const bf16x8 aq0 = ldfrag(qp);
  const bf16x8 aq1 = ldfrag(qp + 32);

  int4 kr[4], vr[4];

  // ---- PASS 1: l = sum 2^(s-16) per q-row (swapped layout: lane-local) ----
  float lsum = 0.f;
  load_k_regs(kr, Kb, 0, t);
  store_k_lds(kr, Ks, t);
  __syncthreads();
  for (int s0 = 0; s0 < 2048; s0 += 128) {
    const bool more = s0 + 128 < 2048;
    if (more) load_k_regs(kr, Kb, s0 + 128, t);  // in flight during compute
    #pragma unroll
    for (int nt2 = 0; nt2 < 4; nt2++) {
      const int koff = ((half * 4 + nt2) * 16 + l15) * 72 + quad * 8;
      f32x4 c = {};
      c = mfma16(ldfrag(Ks + koff), aq0, c);
      c = mfma16(ldfrag(Ks + koff + 32), aq1, c);
      #pragma unroll
      for (int r = 0; r < 4; r++) lsum += exp2f(c[r] * sc2 - C0);
    }
    __syncthreads();
    if (more) store_k_lds(kr, Ks, t);
    __syncthreads();
  }
  lsum += __shfl_xor(lsum, 16);  // combine 4 quads (all belong to q-row l15)
  lsum += __shfl_xor(lsum, 32);
  if (lane < 16) Lb[wave][lane] = lsum;
  __syncthreads();
  const float invl = 1.0f / (Lb[wave][l15] + Lb[wave ^ 2][l15]);

  // ---- PASS 2: recompute scores, weights from regs, P@V ----
  f32x4 acc[4] = {};
  float* wrow =
      w_out + ((size_t)(b * 2048 + qbase + rg * 16 + l15)) * 2048 + half * 64;
  short* pl = Plds + wave * (16 * 72) + l15 * 72;

  load_k_regs(kr, Kb, 0, t);
  load_v_regs(vr, Vb, 0, t);
  __syncthreads();  // pass-1 readers of Ks done (it holds tile 15 now)
  store_k_lds(kr, Ks, t);
  store_v_lds(vr, Vs, t);
  __syncthreads();
  for (int s0 = 0; s0 < 2048; s0 += 128) {
    const bool more = s0 + 128 < 2048;
    if (more) {  // T14: issue next tile early, consume after compute
      load_k_regs(kr, Kb, s0 + 128, t);
      load_v_regs(vr, Vb, s0 + 128, t);
    }
    // QK^T (swapped): C[s=quad*4+r][q=l15]
    f32x4 cc[4];
    #pragma unroll
    for (int nt2 = 0; nt2 < 4; nt2++) {
      const int koff = ((half * 4 + nt2) * 16 + l15) * 72 + quad * 8;
      f32x4 c = {};
      c = mfma16(ldfrag(Ks + koff), aq0, c);
      c = mfma16(ldfrag(Ks + koff + 32), aq1, c);
      cc[nt2] = c;
    }
    // exp, normalize; weights straight from registers; bf16 P to per-wave LDS
    #pragma unroll
    for (int nt2 = 0; nt2 < 4; nt2++) {
      f32x4 w;
      #pragma unroll
      for (int r = 0; r < 4; r++) w[r] = exp2f(cc[nt2][r] * sc2 - C0) * invl;
      *(f32x4*)(wrow + s0 + nt2 * 16 + quad * 4) = w;
      short4 pb;
      pb.x = f2bf(w[0]); pb.y = f2bf(w[1]);
      pb.z = f2bf(w[2]); pb.w = f2bf(w[3]);
      *(short4*)(pl + nt2 * 16 + quad * 4) = pb;
    }
    asm volatile("s_waitcnt lgkmcnt(0)" ::: "memory");
    // P @ V over this wave's s-half
    #pragma unroll
    for (int ks2 = 0; ks2 < 2; ks2++) {
      bf16x8 ap = ldfrag(pl + ks2 * 32 + quad * 8);
      #pragma unroll
      for (int nc = 0; nc < 4; nc++)
        acc[nc] = mfma16(
            ap, ldfrag(Vs + (nc * 16 + l15) * 136 + half * 64 + ks2 * 32 + quad * 8),
            acc[nc]);
    }
    __syncthreads();
    if (more) {
      store_k_lds(kr, Ks, t);
      store_v_lds(vr, Vs, t);
    }
    __syncthreads();
  }
  // O reduce across s-halves (half=1 -> LDS, half=0 adds & stores)
  if (half == 1) {
    #pragma unroll
    for (int nc = 0; nc < 4; nc++)
      #pragma unroll
      for (int r = 0; r < 4; r++)
        Ob[(rg * 16 + quad * 4 + r) * 68 + nc * 16 + l15] = acc[nc][r];
  }
  __syncthreads();
  if (half == 0) {
    #pragma unroll
    for (int nc = 0; nc < 4; nc++)
      #pragma unroll
      for (int r = 0; r < 4; r++) {
        int row = rg * 16 + quad * 4 + r;
        att_out[((size_t)(b * 2048 + qbase + row)) * 64 + nc * 16 + l15] =
            acc[nc][r] + Ob[row * 68 + nc * 16 + l15];
      }
  }
}

// ---------------------------------------------------------------------------
extern "C" void kernel_launch(void* const* d_in, const int* in_sizes, int n_in,
                              void* d_out, int out_size, void* d_ws, size_t ws_size,
                              hipStream_t stream) {
  const float* x  = (const float*)d_in[0];
  const float* Wq = (const float*)d_in[1];
  const float* Wk = (const float*)d_in[2];
  const float* Wv = (const float*)d_in[3];

  char* ws = (char*)d_ws;
  short* wt_hi = (short*)(ws + 0);                 // 196608 B
  short* wt_lo = (short*)(ws + 196608);            // 131072 B
  short* Qg    = (short*)(ws + 327680);            // 2 MB
  short* Kg    = (short*)(ws + 327680 + 2097152);  // 2 MB
  short* VTg   = (short*)(ws + 327680 + 4194304);  // 2 MB  (end ~6.6 MB)

  float* att  = (float*)d_out;
  float* wout = att + (size_t)8 * 2048 * 64;

  hipLaunchKernelGGL(wtrans_kernel, dim3(384), dim3(256), 0, stream,
                     Wq, Wk, Wv, wt_hi, wt_lo);
  hipLaunchKernelGGL(qkv_kernel, dim3(512), dim3(256), 0, stream,
                     x, wt_hi, wt_lo, Qg, Kg, VTg);
  hipLaunchKernelGGL(attn_kernel, dim3(8, 64), dim3(256), 0, stream,
                     Qg, Kg, VTg, att, wout);
}

// Round 4
// 219.782 us; speedup vs baseline: 1.3336x; 1.3336x over previous
//
#include <hip/hip_runtime.h>

// Problem: B=8, S=2048, D=512, DK=64.
// out = attended [8,2048,64] fp32  ||  weights [8,2048,2048] fp32

typedef __bf16 bf16x8 __attribute__((ext_vector_type(8)));
typedef float f32x4 __attribute__((ext_vector_type(4)));

__device__ __forceinline__ short f2bf(float f) {
    unsigned u = __builtin_bit_cast(unsigned, f);
    u = (u + 0x7fffu + ((u >> 16) & 1u)) >> 16;
    return (short)u;
}
__device__ __forceinline__ float bf2f(short h) {
    unsigned u = ((unsigned)(unsigned short)h) << 16;
    return __builtin_bit_cast(float, u);
}
__device__ __forceinline__ bf16x8 ldfrag(const short* p) {
    return *reinterpret_cast<const bf16x8*>(p);
}
__device__ __forceinline__ f32x4 mfma16(bf16x8 a, bf16x8 b, f32x4 c) {
    return __builtin_amdgcn_mfma_f32_16x16x32_bf16(a, b, c, 0, 0, 0);
}

// ---------------------------------------------------------------------------
// Kernel 0: W [512,64] fp32 -> WT [m][64][512] bf16, hi/lo split for q,k.
// ---------------------------------------------------------------------------
__global__ void wtrans_kernel(const float* __restrict__ Wq,
                              const float* __restrict__ Wk,
                              const float* __restrict__ Wv,
                              short* __restrict__ wt_hi,
                              short* __restrict__ wt_lo) {
    int idx = blockIdx.x * 256 + threadIdx.x;  // 3*64*512 = 98304 total
    int k = idx & 511;
    int n = (idx >> 9) & 63;
    int m = idx >> 15;  // 0=q,1=k,2=v
    const float* W = (m == 0) ? Wq : (m == 1) ? Wk : Wv;
    float w = W[k * 64 + n];
    short hi = f2bf(w);
    wt_hi[idx] = hi;
    if (m < 2) wt_lo[idx] = f2bf(w - bf2f(hi));
}

// ---------------------------------------------------------------------------
// Kernel 1: QKV projection (verified round-0 version, unchanged).
// ---------------------------------------------------------------------------
__global__ __launch_bounds__(256) void qkv_kernel(
    const float* __restrict__ x,
    const short* __restrict__ wt_hi, const short* __restrict__ wt_lo,
    short* __restrict__ Qg, short* __restrict__ Kg, short* __restrict__ VTg) {
  __shared__ __align__(16) short Ah[32 * 40], Al[32 * 40];     // also vt reuse
  __shared__ __align__(16) short Bqh[64 * 40], Bql[64 * 40];
  __shared__ __align__(16) short Bkh[64 * 40], Bkl[64 * 40];
  __shared__ __align__(16) short Bvh[64 * 40];
  const int t = threadIdx.x;
  const int wave = t >> 6, lane = t & 63, quad = lane >> 4, l15 = lane & 15;
  const int rg = wave & 1, ntp = wave >> 1;
  const int rbase = blockIdx.x * 32;

  f32x4 accq[2] = {}, acck[2] = {}, accv[2] = {};

  for (int k0 = 0; k0 < 512; k0 += 32) {
    {
      int row = t >> 3, off = (t & 7) << 2;
      float4 v = *(const float4*)(x + (size_t)(rbase + row) * 512 + k0 + off);
      short4 h, lo;
      h.x = f2bf(v.x); lo.x = f2bf(v.x - bf2f(h.x));
      h.y = f2bf(v.y); lo.y = f2bf(v.y - bf2f(h.y));
      h.z = f2bf(v.z); lo.z = f2bf(v.z - bf2f(h.z));
      h.w = f2bf(v.w); lo.w = f2bf(v.w - bf2f(h.w));
      *(short4*)(Ah + row * 40 + off) = h;
      *(short4*)(Al + row * 40 + off) = lo;
    }
    {
      int row = t >> 2, off = (t & 3) << 3;
      int src = row * 512 + k0 + off;
      int dst = row * 40 + off;
      *(int4*)(Bqh + dst) = *(const int4*)(wt_hi + 0 * 32768 + src);
      *(int4*)(Bkh + dst) = *(const int4*)(wt_hi + 1 * 32768 + src);
      *(int4*)(Bvh + dst) = *(const int4*)(wt_hi + 2 * 32768 + src);
      *(int4*)(Bql + dst) = *(const int4*)(wt_lo + 0 * 32768 + src);
      *(int4*)(Bkl + dst) = *(const int4*)(wt_lo + 1 * 32768 + src);
    }
    __syncthreads();
    bf16x8 ah = ldfrag(Ah + (rg * 16 + l15) * 40 + quad * 8);
    bf16x8 al = ldfrag(Al + (rg * 16 + l15) * 40 + quad * 8);
    #pragma unroll
    for (int j = 0; j < 2; j++) {
      const int nt = ntp * 2 + j;
      const int boff = (nt * 16 + l15) * 40 + quad * 8;
      bf16x8 bh = ldfrag(Bqh + boff);
      accq[j] = mfma16(ah, bh, accq[j]);
      accq[j] = mfma16(al, bh, accq[j]);
      accq[j] = mfma16(ah, ldfrag(Bql + boff), accq[j]);
      bh = ldfrag(Bkh + boff);
      acck[j] = mfma16(ah, bh, acck[j]);
      acck[j] = mfma16(al, bh, acck[j]);
      acck[j] = mfma16(ah, ldfrag(Bkl + boff), acck[j]);
      accv[j] = mfma16(ah, ldfrag(Bvh + boff), accv[j]);
    }
    __syncthreads();
  }
  #pragma unroll
  for (int j = 0; j < 2; j++) {
    const int nt = ntp * 2 + j;
    #pragma unroll
    for (int r = 0; r < 4; r++) {
      int row = rbase + rg * 16 + quad * 4 + r;
      int col = nt * 16 + l15;
      Qg[(size_t)row * 64 + col] = f2bf(accq[j][r]);
      Kg[(size_t)row * 64 + col] = f2bf(acck[j][r]);
    }
  }
  short* vt = Ah;
  #pragma unroll
  for (int j = 0; j < 2; j++) {
    const int col = (ntp * 2 + j) * 16 + l15;
    short4 p;
    p.x = f2bf(accv[j][0]); p.y = f2bf(accv[j][1]);
    p.z = f2bf(accv[j][2]); p.w = f2bf(accv[j][3]);
    *(short4*)(vt + col * 40 + rg * 16 + quad * 4) = p;
  }
  __syncthreads();
  {
    const int bidx = rbase >> 11;
    int c = t >> 2, ch = (t & 3) << 3;
    *(int4*)(VTg + (size_t)bidx * 131072 + (size_t)c * 2048 + (rbase & 2047) + ch) =
        *(const int4*)(vt + c * 40 + ch);
  }
}

// ---------------------------------------------------------------------------
// Attention as 3 kernels: high occupancy AND LDS staging (lesson of R1-R3:
// scattered per-wave global loads are latency death; staging at 2 wg/CU
// lockstep never reaches roofline; need both staging and >=5 wg/CU).
//
// lpass: grid(8,64,4) = 2048 wg (8/CU, LDS 18KB). Partial softmax denom per
//        512-col s-chunk -> Lpart. Swapped QK: mfma(K,Q), C[s=quad*4+r][q=l15],
//        lane-local lsum, 2 shuffles at end. (= R3's verified pass-1.)
// wo:    grid(8,32,4) = 1024 wg (5/CU, LDS 27.6KB). 64 q-rows/wg, wave owns
//        16 q-rows x full 64-wide s-tile (no cross-wave reduce). Recomputes
//        QK, w = exp*invl, weights stored straight from registers (R1
//        pattern); normalized bf16 P -> per-wave LDS -> PV -> Opart.
// finalize: att = sum of 4 normalized O-partials (no invl: P was normalized).
// Constant-shift softmax (C=16, provably safe: |s*log2e| < 27).
// ---------------------------------------------------------------------------
__global__ __launch_bounds__(256) void lpass_kernel(
    const short* __restrict__ Qg, const short* __restrict__ Kg,
    float* __restrict__ Lpart) {
  __shared__ __align__(16) short Ks[128 * 72];  // 18432 B
  __shared__ float Lb[4][16];
  const int t = threadIdx.x;
  const int wave = t >> 6, lane = t & 63, quad = lane >> 4, l15 = lane & 15;
  const int rg = wave & 1, half = wave >> 1;
  const int b = blockIdx.x, qbase = blockIdx.y * 32, sc = blockIdx.z;
  const float sc2 = 0.125f * 1.44269504088896340736f;  // (1/sqrt(64))*log2(e)
  const float C0 = 16.0f;

  const short* Kb = Kg + (size_t)b * 131072;
  const short* qp =
      Qg + (size_t)(b * 2048 + qbase + rg * 16 + l15) * 64 + quad * 8;
  const bf16x8 aq0 = ldfrag(qp);
  const bf16x8 aq1 = ldfrag(qp + 32);

  float lsum = 0.f;
  for (int s0 = 0; s0 < 512; s0 += 128) {
    const int sg = sc * 512 + s0;
    #pragma unroll
    for (int i = 0; i < 4; i++) {
      int c = t + i * 256, row = c >> 3, off = (c & 7) << 3;
      *(int4*)(Ks + row * 72 + off) =
          *(const int4*)(Kb + (size_t)(sg + row) * 64 + off);
    }
    __syncthreads();
    #pragma unroll
    for (int nt2 = 0; nt2 < 4; nt2++) {
      const int koff = ((half * 4 + nt2) * 16 + l15) * 72 + quad * 8;
      f32x4 c = {};
      c = mfma16(ldfrag(Ks + koff), aq0, c);
      c = mfma16(ldfrag(Ks + koff + 32), aq1, c);
      #pragma unroll
      for (int r = 0; r < 4; r++) lsum += exp2f(c[r] * sc2 - C0);
    }
    __syncthreads();
  }
  lsum += __shfl_xor(lsum, 16);  // combine 4 quads (all belong to q-row l15)
  lsum += __shfl_xor(lsum, 32);
  if (lane < 16) Lb[wave][lane] = lsum;
  __syncthreads();
  if (half == 0 && lane < 16)
    Lpart[(size_t)sc * 16384 + b * 2048 + qbase + rg * 16 + lane] =
        Lb[wave][lane] + Lb[wave ^ 2][lane];
}

__global__ __launch_bounds__(256) void wo_kernel(
    const short* __restrict__ Qg, const short* __restrict__ Kg,
    const short* __restrict__ VTg, const float* __restrict__ Lpart,
    float* __restrict__ w_out, float* __restrict__ Opart) {
  __shared__ __align__(16) short Ks[64 * 72];        // 9216 B
  __shared__ __align__(16) short Vs[64 * 72];        // 9216 B (VT: [dk][s])
  __shared__ __align__(16) short Plds[4 * 16 * 72];  // 9216 B, per-wave
  const int t = threadIdx.x;
  const int wave = t >> 6, lane = t & 63, quad = lane >> 4, l15 = lane & 15;
  const int b = blockIdx.x, qbase = blockIdx.y * 64, sc = blockIdx.z;
  const float sc2 = 0.125f * 1.44269504088896340736f;
  const float C0 = 16.0f;

  const short* Kb = Kg + (size_t)b * 131072;
  const short* Vb = VTg + (size_t)b * 131072;
  // wave owns q-rows [qbase + wave*16, +16); lane l15 = its q-row
  const int qrow = b * 2048 + qbase + wave * 16 + l15;
  const short* qp = Qg + (size_t)qrow * 64 + quad * 8;
  const bf16x8 aq0 = ldfrag(qp);
  const bf16x8 aq1 = ldfrag(qp + 32);
  const float invl = 1.0f / (Lpart[qrow] + Lpart[16384 + qrow] +
                             Lpart[32768 + qrow] + Lpart[49152 + qrow]);

  f32x4 acc[4] = {};
  float* wrow = w_out + (size_t)qrow * 2048 + sc * 512;
  short* pl = Plds + wave * (16 * 72) + l15 * 72;

  for (int s0 = 0; s0 < 512; s0 += 64) {
    const int sg = sc * 512 + s0;
    // stage K tile (64 s x 64 dk) and VT tile (64 dk x 64 s): 2+2 int4/thread
    #pragma unroll
    for (int i = 0; i < 2; i++) {
      int c = t + i * 256, row = c >> 3, off = (c & 7) << 3;
      *(int4*)(Ks + row * 72 + off) =
          *(const int4*)(Kb + (size_t)(sg + row) * 64 + off);
      *(int4*)(Vs + row * 72 + off) =
          *(const int4*)(Vb + (size_t)row * 2048 + sg + off);
    }
    __syncthreads();
    // QK^T (swapped): C[s = quad*4+r][q = l15]
    #pragma unroll
    for (int nt2 = 0; nt2 < 4; nt2++) {
      const int koff = (nt2 * 16 + l15) * 72 + quad * 8;
      f32x4 c = {};
      c = mfma16(ldfrag(Ks + koff), aq0, c);
      c = mfma16(ldfrag(Ks + koff + 32), aq1, c);
      f32x4 w;
      #pragma unroll
      for (int r = 0; r < 4; r++) w[r] = exp2f(c[r] * sc2 - C0) * invl;
      *(f32x4*)(wrow + s0 + nt2 * 16 + quad * 4) = w;  // weights from regs
      short4 pb;
      pb.x = f2bf(w[0]); pb.y = f2bf(w[1]);
      pb.z = f2bf(w[2]); pb.w = f2bf(w[3]);
      *(short4*)(pl + nt2 * 16 + quad * 4) = pb;       // normalized bf16 P
    }
    asm volatile("s_waitcnt lgkmcnt(0)" ::: "memory");  // per-wave P fence
    // P @ V over this tile's 64 s-cols
    #pragma unroll
    for (int ks2 = 0; ks2 < 2; ks2++) {
      bf16x8 ap = ldfrag(pl + ks2 * 32 + quad * 8);
      #pragma unroll
      for (int nc = 0; nc < 4; nc++)
        acc[nc] = mfma16(
            ap, ldfrag(Vs + (nc * 16 + l15) * 72 + ks2 * 32 + quad * 8),
            acc[nc]);
    }
    __syncthreads();
  }
  // O partial (already normalized): C[row = q local quad*4+r][col = dk]
  #pragma unroll
  for (int nc = 0; nc < 4; nc++)
    #pragma unroll
    for (int r = 0; r < 4; r++)
      Opart[((size_t)sc * 16384 + b * 2048 + qbase + wave * 16 + quad * 4 + r) *
                64 + nc * 16 + l15] = acc[nc][r];
}

__global__ __launch_bounds__(256) void finalize_kernel(
    const float* __restrict__ Opart, float* __restrict__ att_out) {
  int idx = blockIdx.x * 256 + threadIdx.x;  // 262144 = 16384 rows * 16 f32x4
  int row = idx >> 4, c4 = (idx & 15) << 2;
  size_t base = (size_t)row * 64 + c4;
  f32x4 o = *(const f32x4*)(Opart + base);
  o += *(const f32x4*)(Opart + 1048576 + base);
  o += *(const f32x4*)(Opart + 2097152 + base);
  o += *(const f32x4*)(Opart + 3145728 + base);
  *(f32x4*)(att_out + base) = o;
}

// ---------------------------------------------------------------------------
extern "C" void kernel_launch(void* const* d_in, const int* in_sizes, int n_in,
                              void* d_out, int out_size, void* d_ws, size_t ws_size,
                              hipStream_t stream) {
  const float* x  = (const float*)d_in[0];
  const float* Wq = (const float*)d_in[1];
  const float* Wk = (const float*)d_in[2];
  const float* Wv = (const float*)d_in[3];

  char* ws = (char*)d_ws;
  short* wt_hi = (short*)(ws + 0);                 // 196608 B
  short* wt_lo = (short*)(ws + 196608);            // 131072 B
  short* Qg    = (short*)(ws + 327680);            // 2 MB
  short* Kg    = (short*)(ws + 327680 + 2097152);  // 2 MB
  short* VTg   = (short*)(ws + 327680 + 4194304);  // 2 MB
  float* Lpart = (float*)(ws + 6619136);           // 4*16384*4 = 256 KB
  float* Opart = (float*)(ws + 6881280);           // 4*1048576*4 = 16 MB (end ~23.7 MB)

  float* att  = (float*)d_out;
  float* wout = att + (size_t)8 * 2048 * 64;

  hipLaunchKernelGGL(wtrans_kernel, dim3(384), dim3(256), 0, stream,
                     Wq, Wk, Wv, wt_hi, wt_lo);
  hipLaunchKernelGGL(qkv_kernel, dim3(512), dim3(256), 0, stream,
                     x, wt_hi, wt_lo, Qg, Kg, VTg);
  hipLaunchKernelGGL(lpass_kernel, dim3(8, 64, 4), dim3(256), 0, stream,
                     Qg, Kg, Lpart);
  hipLaunchKernelGGL(wo_kernel, dim3(8, 32, 4), dim3(256), 0, stream,
                     Qg, Kg, VTg, Lpart, wout, Opart);
  hipLaunchKernelGGL(finalize_kernel, dim3(1024), dim3(256), 0, stream,
                     Opart, att);
}

// Round 5
// 215.816 us; speedup vs baseline: 1.3582x; 1.0184x over previous
//
#include <hip/hip_runtime.h>

// Problem: B=8, S=2048, D=512, DK=64.
// out = attended [8,2048,64] fp32  ||  weights [8,2048,2048] fp32

typedef __bf16 bf16x8 __attribute__((ext_vector_type(8)));
typedef float f32x4 __attribute__((ext_vector_type(4)));
typedef short short8_t __attribute__((ext_vector_type(8)));

__device__ __forceinline__ short f2bf(float f) {
    unsigned u = __builtin_bit_cast(unsigned, f);
    u = (u + 0x7fffu + ((u >> 16) & 1u)) >> 16;
    return (short)u;
}
__device__ __forceinline__ float bf2f(short h) {
    unsigned u = ((unsigned)(unsigned short)h) << 16;
    return __builtin_bit_cast(float, u);
}
__device__ __forceinline__ bf16x8 ldfrag(const short* p) {
    return *reinterpret_cast<const bf16x8*>(p);
}
__device__ __forceinline__ f32x4 mfma16(bf16x8 a, bf16x8 b, f32x4 c) {
    return __builtin_amdgcn_mfma_f32_16x16x32_bf16(a, b, c, 0, 0, 0);
}

// ---------------------------------------------------------------------------
// Kernel 0: W [512,64] fp32 -> WT [m][64][512] bf16, hi/lo split for q,k.
// ---------------------------------------------------------------------------
__global__ void wtrans_kernel(const float* __restrict__ Wq,
                              const float* __restrict__ Wk,
                              const float* __restrict__ Wv,
                              short* __restrict__ wt_hi,
                              short* __restrict__ wt_lo) {
    int idx = blockIdx.x * 256 + threadIdx.x;  // 3*64*512 = 98304 total
    int k = idx & 511;
    int n = (idx >> 9) & 63;
    int m = idx >> 15;  // 0=q,1=k,2=v
    const float* W = (m == 0) ? Wq : (m == 1) ? Wk : Wv;
    float w = W[k * 64 + n];
    short hi = f2bf(w);
    wt_hi[idx] = hi;
    if (m < 2) wt_lo[idx] = f2bf(w - bf2f(hi));
}

// ---------------------------------------------------------------------------
// Kernel 1: QKV projection (verified round-0 version, unchanged).
// ---------------------------------------------------------------------------
__global__ __launch_bounds__(256) void qkv_kernel(
    const float* __restrict__ x,
    const short* __restrict__ wt_hi, const short* __restrict__ wt_lo,
    short* __restrict__ Qg, short* __restrict__ Kg, short* __restrict__ VTg) {
  __shared__ __align__(16) short Ah[32 * 40], Al[32 * 40];     // also vt reuse
  __shared__ __align__(16) short Bqh[64 * 40], Bql[64 * 40];
  __shared__ __align__(16) short Bkh[64 * 40], Bkl[64 * 40];
  __shared__ __align__(16) short Bvh[64 * 40];
  const int t = threadIdx.x;
  const int wave = t >> 6, lane = t & 63, quad = lane >> 4, l15 = lane & 15;
  const int rg = wave & 1, ntp = wave >> 1;
  const int rbase = blockIdx.x * 32;

  f32x4 accq[2] = {}, acck[2] = {}, accv[2] = {};

  for (int k0 = 0; k0 < 512; k0 += 32) {
    {
      int row = t >> 3, off = (t & 7) << 2;
      float4 v = *(const float4*)(x + (size_t)(rbase + row) * 512 + k0 + off);
      short4 h, lo;
      h.x = f2bf(v.x); lo.x = f2bf(v.x - bf2f(h.x));
      h.y = f2bf(v.y); lo.y = f2bf(v.y - bf2f(h.y));
      h.z = f2bf(v.z); lo.z = f2bf(v.z - bf2f(h.z));
      h.w = f2bf(v.w); lo.w = f2bf(v.w - bf2f(h.w));
      *(short4*)(Ah + row * 40 + off) = h;
      *(short4*)(Al + row * 40 + off) = lo;
    }
    {
      int row = t >> 2, off = (t & 3) << 3;
      int src = row * 512 + k0 + off;
      int dst = row * 40 + off;
      *(int4*)(Bqh + dst) = *(const int4*)(wt_hi + 0 * 32768 + src);
      *(int4*)(Bkh + dst) = *(const int4*)(wt_hi + 1 * 32768 + src);
      *(int4*)(Bvh + dst) = *(const int4*)(wt_hi + 2 * 32768 + src);
      *(int4*)(Bql + dst) = *(const int4*)(wt_lo + 0 * 32768 + src);
      *(int4*)(Bkl + dst) = *(const int4*)(wt_lo + 1 * 32768 + src);
    }
    __syncthreads();
    bf16x8 ah = ldfrag(Ah + (rg * 16 + l15) * 40 + quad * 8);
    bf16x8 al = ldfrag(Al + (rg * 16 + l15) * 40 + quad * 8);
    #pragma unroll
    for (int j = 0; j < 2; j++) {
      const int nt = ntp * 2 + j;
      const int boff = (nt * 16 + l15) * 40 + quad * 8;
      bf16x8 bh = ldfrag(Bqh + boff);
      accq[j] = mfma16(ah, bh, accq[j]);
      accq[j] = mfma16(al, bh, accq[j]);
      accq[j] = mfma16(ah, ldfrag(Bql + boff), accq[j]);
      bh = ldfrag(Bkh + boff);
      acck[j] = mfma16(ah, bh, acck[j]);
      acck[j] = mfma16(al, bh, acck[j]);
      acck[j] = mfma16(ah, ldfrag(Bkl + boff), acck[j]);
      accv[j] = mfma16(ah, ldfrag(Bvh + boff), accv[j]);
    }
    __syncthreads();
  }
  #pragma unroll
  for (int j = 0; j < 2; j++) {
    const int nt = ntp * 2 + j;
    #pragma unroll
    for (int r = 0; r < 4; r++) {
      int row = rbase + rg * 16 + quad * 4 + r;
      int col = nt * 16 + l15;
      Qg[(size_t)row * 64 + col] = f2bf(accq[j][r]);
      Kg[(size_t)row * 64 + col] = f2bf(acck[j][r]);
    }
  }
  short* vt = Ah;
  #pragma unroll
  for (int j = 0; j < 2; j++) {
    const int col = (ntp * 2 + j) * 16 + l15;
    short4 p;
    p.x = f2bf(accv[j][0]); p.y = f2bf(accv[j][1]);
    p.z = f2bf(accv[j][2]); p.w = f2bf(accv[j][3]);
    *(short4*)(vt + col * 40 + rg * 16 + quad * 4) = p;
  }
  __syncthreads();
  {
    const int bidx = rbase >> 11;
    int c = t >> 2, ch = (t & 3) << 3;
    *(int4*)(VTg + (size_t)bidx * 131072 + (size_t)c * 2048 + (rbase & 2047) + ch) =
        *(const int4*)(vt + c * 40 + ch);
  }
}

// ---------------------------------------------------------------------------
// Attention as 3 kernels (R4-verified structure: staging + >=4 wg/CU).
//
// lpass: grid(8,32,4) = 1024 wg. 64 q-rows/wg: wave owns 16 q-rows
//        (wo-verified pattern), processes ALL 8 nt of the staged 128-row
//        K tile. Half the staging/barriers of R4; no cross-wave reduce.
// wo:    grid(8,32,4) = 1024 wg (5/CU). Unchanged except Opart -> bf16.
// finalize: att = sum of 4 normalized bf16 O-partials (fp32 accumulate).
// Constant-shift softmax (C=16, provably safe: |s*log2e| < 27).
// ---------------------------------------------------------------------------
__global__ __launch_bounds__(256) void lpass_kernel(
    const short* __restrict__ Qg, const short* __restrict__ Kg,
    float* __restrict__ Lpart) {
  __shared__ __align__(16) short Ks[128 * 72];  // 18432 B
  const int t = threadIdx.x;
  const int wave = t >> 6, lane = t & 63, quad = lane >> 4, l15 = lane & 15;
  const int b = blockIdx.x, qbase = blockIdx.y * 64, sc = blockIdx.z;
  const float sc2 = 0.125f * 1.44269504088896340736f;  // (1/sqrt(64))*log2(e)
  const float C0 = 16.0f;

  const short* Kb = Kg + (size_t)b * 131072;
  // wave owns q-rows [qbase + wave*16, +16); lane l15 = its q-row
  const int qrow = b * 2048 + qbase + wave * 16 + l15;
  const short* qp = Qg + (size_t)qrow * 64 + quad * 8;
  const bf16x8 aq0 = ldfrag(qp);
  const bf16x8 aq1 = ldfrag(qp + 32);

  float lsum = 0.f;
  for (int s0 = 0; s0 < 512; s0 += 128) {
    const int sg = sc * 512 + s0;
    #pragma unroll
    for (int i = 0; i < 4; i++) {
      int c = t + i * 256, row = c >> 3, off = (c & 7) << 3;
      *(int4*)(Ks + row * 72 + off) =
          *(const int4*)(Kb + (size_t)(sg + row) * 64 + off);
    }
    __syncthreads();
    #pragma unroll
    for (int nt = 0; nt < 8; nt++) {
      const int koff = (nt * 16 + l15) * 72 + quad * 8;
      f32x4 c = {};
      c = mfma16(ldfrag(Ks + koff), aq0, c);
      c = mfma16(ldfrag(Ks + koff + 32), aq1, c);
      #pragma unroll
      for (int r = 0; r < 4; r++) lsum += exp2f(c[r] * sc2 - C0);
    }
    __syncthreads();
  }
  lsum += __shfl_xor(lsum, 16);  // combine 4 quads (all belong to q-row l15)
  lsum += __shfl_xor(lsum, 32);
  if (lane < 16)
    Lpart[(size_t)sc * 16384 + b * 2048 + qbase + wave * 16 + lane] = lsum;
}

__global__ __launch_bounds__(256) void wo_kernel(
    const short* __restrict__ Qg, const short* __restrict__ Kg,
    const short* __restrict__ VTg, const float* __restrict__ Lpart,
    float* __restrict__ w_out, short* __restrict__ Opart) {
  __shared__ __align__(16) short Ks[64 * 72];        // 9216 B
  __shared__ __align__(16) short Vs[64 * 72];        // 9216 B (VT: [dk][s])
  __shared__ __align__(16) short Plds[4 * 16 * 72];  // 9216 B, per-wave
  const int t = threadIdx.x;
  const int wave = t >> 6, lane = t & 63, quad = lane >> 4, l15 = lane & 15;
  const int b = blockIdx.x, qbase = blockIdx.y * 64, sc = blockIdx.z;
  const float sc2 = 0.125f * 1.44269504088896340736f;
  const float C0 = 16.0f;

  const short* Kb = Kg + (size_t)b * 131072;
  const short* Vb = VTg + (size_t)b * 131072;
  // wave owns q-rows [qbase + wave*16, +16); lane l15 = its q-row
  const int qrow = b * 2048 + qbase + wave * 16 + l15;
  const short* qp = Qg + (size_t)qrow * 64 + quad * 8;
  const bf16x8 aq0 = ldfrag(qp);
  const bf16x8 aq1 = ldfrag(qp + 32);
  const float invl = 1.0f / (Lpart[qrow] + Lpart[16384 + qrow] +
                             Lpart[32768 + qrow] + Lpart[49152 + qrow]);

  f32x4 acc[4] = {};
  float* wrow = w_out + (size_t)qrow * 2048 + sc * 512;
  short* pl = Plds + wave * (16 * 72) + l15 * 72;

  for (int s0 = 0; s0 < 512; s0 += 64) {
    const int sg = sc * 512 + s0;
    // stage K tile (64 s x 64 dk) and VT tile (64 dk x 64 s): 2+2 int4/thread
    #pragma unroll
    for (int i = 0; i < 2; i++) {
      int c = t + i * 256, row = c >> 3, off = (c & 7) << 3;
      *(int4*)(Ks + row * 72 + off) =
          *(const int4*)(Kb + (size_t)(sg + row) * 64 + off);
      *(int4*)(Vs + row * 72 + off) =
          *(const int4*)(Vb + (size_t)row * 2048 + sg + off);
    }
    __syncthreads();
    // QK^T (swapped): C[s = quad*4+r][q = l15]
    #pragma unroll
    for (int nt2 = 0; nt2 < 4; nt2++) {
      const int koff = (nt2 * 16 + l15) * 72 + quad * 8;
      f32x4 c = {};
      c = mfma16(ldfrag(Ks + koff), aq0, c);
      c = mfma16(ldfrag(Ks + koff + 32), aq1, c);
      f32x4 w;
      #pragma unroll
      for (int r = 0; r < 4; r++) w[r] = exp2f(c[r] * sc2 - C0) * invl;
      *(f32x4*)(wrow + s0 + nt2 * 16 + quad * 4) = w;  // weights from regs
      short4 pb;
      pb.x = f2bf(w[0]); pb.y = f2bf(w[1]);
      pb.z = f2bf(w[2]); pb.w = f2bf(w[3]);
      *(short4*)(pl + nt2 * 16 + quad * 4) = pb;       // normalized bf16 P
    }
    asm volatile("s_waitcnt lgkmcnt(0)" ::: "memory");  // per-wave P fence
    // P @ V over this tile's 64 s-cols
    #pragma unroll
    for (int ks2 = 0; ks2 < 2; ks2++) {
      bf16x8 ap = ldfrag(pl + ks2 * 32 + quad * 8);
      #pragma unroll
      for (int nc = 0; nc < 4; nc++)
        acc[nc] = mfma16(
            ap, ldfrag(Vs + (nc * 16 + l15) * 72 + ks2 * 32 + quad * 8),
            acc[nc]);
    }
    __syncthreads();
  }
  // O partial (already normalized), bf16: C[row = quad*4+r][col = dk]
  #pragma unroll
  for (int nc = 0; nc < 4; nc++)
    #pragma unroll
    for (int r = 0; r < 4; r++)
      Opart[((size_t)sc * 16384 + b * 2048 + qbase + wave * 16 + quad * 4 + r) *
                64 + nc * 16 + l15] = f2bf(acc[nc][r]);
}

__global__ __launch_bounds__(256) void finalize_kernel(
    const short* __restrict__ Opart, float* __restrict__ att_out) {
  int idx = blockIdx.x * 256 + threadIdx.x;  // 131072 = 16384 rows * 8 groups
  int row = idx >> 3, c8 = (idx & 7) << 3;
  size_t base = (size_t)row * 64 + c8;
  short8_t p0 = *(const short8_t*)(Opart + base);
  short8_t p1 = *(const short8_t*)(Opart + 1048576 + base);
  short8_t p2 = *(const short8_t*)(Opart + 2097152 + base);
  short8_t p3 = *(const short8_t*)(Opart + 3145728 + base);
  f32x4 oA, oB;
  #pragma unroll
  for (int j = 0; j < 4; j++) {
    oA[j] = (bf2f(p0[j]) + bf2f(p1[j])) + (bf2f(p2[j]) + bf2f(p3[j]));
    oB[j] = (bf2f(p0[4 + j]) + bf2f(p1[4 + j])) +
            (bf2f(p2[4 + j]) + bf2f(p3[4 + j]));
  }
  *(f32x4*)(att_out + base) = oA;
  *(f32x4*)(att_out + base + 4) = oB;
}

// ---------------------------------------------------------------------------
extern "C" void kernel_launch(void* const* d_in, const int* in_sizes, int n_in,
                              void* d_out, int out_size, void* d_ws, size_t ws_size,
                              hipStream_t stream) {
  const float* x  = (const float*)d_in[0];
  const float* Wq = (const float*)d_in[1];
  const float* Wk = (const float*)d_in[2];
  const float* Wv = (const float*)d_in[3];

  char* ws = (char*)d_ws;
  short* wt_hi = (short*)(ws + 0);                 // 196608 B
  short* wt_lo = (short*)(ws + 196608);            // 131072 B
  short* Qg    = (short*)(ws + 327680);            // 2 MB
  short* Kg    = (short*)(ws + 327680 + 2097152);  // 2 MB
  short* VTg   = (short*)(ws + 327680 + 4194304);  // 2 MB
  float* Lpart = (float*)(ws + 6619136);           // 4*16384*4 = 256 KB
  short* Opart = (short*)(ws + 6881280);           // 4*1048576*2 = 8 MB (end ~15 MB)

  float* att  = (float*)d_out;
  float* wout = att + (size_t)8 * 2048 * 64;

  hipLaunchKernelGGL(wtrans_kernel, dim3(384), dim3(256), 0, stream,
                     Wq, Wk, Wv, wt_hi, wt_lo);
  hipLaunchKernelGGL(qkv_kernel, dim3(512), dim3(256), 0, stream,
                     x, wt_hi, wt_lo, Qg, Kg, VTg);
  hipLaunchKernelGGL(lpass_kernel, dim3(8, 32, 4), dim3(256), 0, stream,
                     Qg, Kg, Lpart);
  hipLaunchKernelGGL(wo_kernel, dim3(8, 32, 4), dim3(256), 0, stream,
                     Qg, Kg, VTg, Lpart, wout, Opart);
  hipLaunchKernelGGL(finalize_kernel, dim3(512), dim3(256), 0, stream,
                     Opart, att);
}